// Round 26
// baseline (204.152 us; speedup 1.0000x reference)
//
#include <hip/hip_runtime.h>
#include <hip/hip_bf16.h>
#include <hip/hip_cooperative_groups.h>
#include <math.h>

namespace cg = cooperative_groups;

#define B_N 8
#define S_N 2048
#define C_N 384
#define D_N 64
#define NPART 2           // triangular split factor (parts always non-empty)

typedef __bf16 bf16x8 __attribute__((ext_vector_type(8)));
typedef float f32x4 __attribute__((ext_vector_type(4)));

static __device__ __forceinline__ bf16x8 ldfrag(const __bf16* p) {
  return *reinterpret_cast<const bf16x8*>(p);
}

// async 16B global -> LDS (linear dest, per-lane global src)
static __device__ __forceinline__ void gload16(void* lds, const void* gsrc) {
  __builtin_amdgcn_global_load_lds(
      (const __attribute__((address_space(1))) unsigned int*)gsrc,
      (__attribute__((address_space(3))) unsigned int*)lds, 16, 0, 0);
}

// ---------------------------------------------------------------------------
// ONE cooperative kernel, 5 phases, 4 grid syncs. 256 blocks x 512 threads
// (2 blocks/CU co-resident). Phase bodies are the measured R23/R24 kernels.
// ---------------------------------------------------------------------------
__global__ __launch_bounds__(512) void fused(
    const float* __restrict__ x,
    const float* __restrict__ Wq, const float* __restrict__ Wk,
    const float* __restrict__ Wv,
    __bf16* __restrict__ xb, __bf16* __restrict__ Wt,
    __bf16* __restrict__ Qb, __bf16* __restrict__ Kb, __bf16* __restrict__ Vt,
    float* __restrict__ zpart, float* __restrict__ opart,
    float* __restrict__ out) {
  cg::grid_group grid = cg::this_grid();

  // LDS union across phases (max: P3 = 16K KT + 16K VT + 18K P = 51200 B)
  __shared__ __align__(16) unsigned char smem[51200];

  const int blk = blockIdx.x;                      // 0..255
  const int t = threadIdx.x;                       // 0..511
  const int lane = t & 63, lr = lane & 15, lg = lane >> 4;

  // ===== Phase 0: W transpose+scale -> Wt ; x -> bf16 (both coalesced) =====
  {
    const int gtid = blk * 512 + t;
    const int gsz = 256 * 512;
    for (int ch = gtid; ch < 9216; ch += gsz) {    // 3*64*384 / 8
      const int idx = ch * 8;
      const int m = idx / (64 * C_N);
      const int r = idx % (64 * C_N);
      const int d = r / C_N;
      const int c = r % C_N;                       // c % 8 == 0
      const float* W = (m == 0) ? Wq : (m == 1) ? Wk : Wv;
      const float s = (m == 0) ? 0.125f : 1.0f;
      bf16x8 v;
#pragma unroll
      for (int i = 0; i < 8; ++i) v[i] = (__bf16)(W[(c + i) * 64 + d] * s);
      *reinterpret_cast<bf16x8*>(Wt + idx) = v;
    }
    for (size_t ch = gtid; ch < (size_t)B_N * S_N * C_N / 8; ch += gsz) {
      const size_t idx = ch * 8;
      const float4 a = *reinterpret_cast<const float4*>(x + idx);
      const float4 b = *reinterpret_cast<const float4*>(x + idx + 4);
      bf16x8 v;
      v[0] = (__bf16)a.x; v[1] = (__bf16)a.y; v[2] = (__bf16)a.z; v[3] = (__bf16)a.w;
      v[4] = (__bf16)b.x; v[5] = (__bf16)b.y; v[6] = (__bf16)b.z; v[7] = (__bf16)b.w;
      *reinterpret_cast<bf16x8*>(xb + idx) = v;
    }
  }
  grid.sync();

  // ===== Phase 1: QKV projection (R24 body; 64 rows/block, 4 x 16-row) =====
  {
    __bf16 (*vtile)[68] = reinterpret_cast<__bf16(*)[68]>(smem);
    const int w = t >> 6;
    const int mat = w >> 1, nh = w & 1;            // valid for w < 6
#pragma unroll
    for (int r16 = 0; r16 < 4; ++r16) {
      const int row0 = blk * 64 + r16 * 16;
      if (w < 6) {
        const __bf16* xr = xb + (size_t)(row0 + lr) * C_N;
        const __bf16* Wm = Wt + (size_t)mat * 64 * C_N;
        f32x4 acc0 = {0.f, 0.f, 0.f, 0.f};
        f32x4 acc1 = {0.f, 0.f, 0.f, 0.f};
        bf16x8 a   = ldfrag(xr + lg * 8);
        bf16x8 bw0 = ldfrag(Wm + (size_t)(nh * 32 + lr) * C_N + lg * 8);
        bf16x8 bw1 = ldfrag(Wm + (size_t)(nh * 32 + 16 + lr) * C_N + lg * 8);
        for (int kk = 0; kk < C_N / 32; ++kk) {
          const int kn = (kk + 1 < C_N / 32) ? kk + 1 : kk;
          const bf16x8 an  = ldfrag(xr + kn * 32 + lg * 8);
          const bf16x8 b0n = ldfrag(Wm + (size_t)(nh * 32 + lr) * C_N + kn * 32 + lg * 8);
          const bf16x8 b1n = ldfrag(Wm + (size_t)(nh * 32 + 16 + lr) * C_N + kn * 32 + lg * 8);
          acc0 = __builtin_amdgcn_mfma_f32_16x16x32_bf16(a, bw0, acc0, 0, 0, 0);
          acc1 = __builtin_amdgcn_mfma_f32_16x16x32_bf16(a, bw1, acc1, 0, 0, 0);
          a = an; bw0 = b0n; bw1 = b1n;
        }
        if (mat < 2) {
          __bf16* outp = (mat == 0) ? Qb : Kb;
#pragma unroll
          for (int r = 0; r < 4; ++r) {
            outp[(size_t)(row0 + lg * 4 + r) * 64 + nh * 32 + lr] = (__bf16)acc0[r];
            outp[(size_t)(row0 + lg * 4 + r) * 64 + nh * 32 + 16 + lr] = (__bf16)acc1[r];
          }
        } else {
#pragma unroll
          for (int r = 0; r < 4; ++r) {
            vtile[lg * 4 + r][nh * 32 + lr] = (__bf16)acc0[r];
            vtile[lg * 4 + r][nh * 32 + 16 + lr] = (__bf16)acc1[r];
          }
        }
      }
      __syncthreads();
      const int b = row0 >> 11, s0 = row0 & (S_N - 1);
      for (int idx = t; idx < 64 * 16; idx += 512) {
        const int d = idx >> 4, s2 = idx & 15;
        Vt[((size_t)b * D_N + d) * S_N + s0 + s2] = vtile[s2][d];
      }
      __syncthreads();
    }
  }
  grid.sync();

  // ===== Phase 2: column denominator partials (R23 body, NPART=2) =====
  {
    __bf16 (*QT)[64][64] = reinterpret_cast<__bf16(*)[64][64]>(smem);
    const int b  = blk & 7;                        // XCD swizzle
    const int jb = (blk >> 3) & 15;                // 128-col block
    const int h  = blk >> 7;                       // 0..1
    const int j0 = jb * 128;
    const int q = t >> 6;                          // wave = j-tile 0..7

    const int n = 32 - 2 * jb;                     // i-tiles (even, >= 2)
    const int itStart = 2 * jb + (n * h) / NPART;
    const int itEnd   = 2 * jb + (n * (h + 1)) / NPART;
    float* zout = zpart + (size_t)h * B_N * S_N + (size_t)b * S_N;

    const __bf16* Qp = Qb + (size_t)b * S_N * 64;
    const __bf16* Kp = Kb + (size_t)b * S_N * 64;

    const int jg = j0 + q * 16 + lr;               // this lane's column
    const bf16x8 bk0 = ldfrag(Kp + (size_t)jg * 64 + lg * 8);
    const bf16x8 bk1 = ldfrag(Kp + (size_t)jg * 64 + 32 + lg * 8);

    const int r0 = t >> 3, c0 = t & 7;
    const int gq = c0 ^ (r0 & 7);                  // inverse-swizzled source

#define STAGE_Q(BUF, TILE) \
    gload16(&QT[BUF][r0][c0 * 8], Qp + (size_t)((TILE) * 64 + r0) * 64 + gq * 8)

    STAGE_Q(0, itStart);
    __syncthreads();

    float z = 0.f;
    int cur = 0;
    for (int it = itStart; it < itEnd; ++it) {
      const int i0 = it * 64;
      if (it + 1 < itEnd) STAGE_Q(cur ^ 1, it + 1);
#pragma unroll
      for (int s = 0; s < 4; ++s) {
        const int arow = s * 16 + lr;
        const bf16x8 aq0 = ldfrag(&QT[cur][arow][(lg ^ (arow & 7)) * 8]);
        const bf16x8 aq1 = ldfrag(&QT[cur][arow][((4 + lg) ^ (arow & 7)) * 8]);
        f32x4 s4 = {0.f, 0.f, 0.f, 0.f};
        s4 = __builtin_amdgcn_mfma_f32_16x16x32_bf16(aq0, bk0, s4, 0, 0, 0);
        s4 = __builtin_amdgcn_mfma_f32_16x16x32_bf16(aq1, bk1, s4, 0, 0, 0);
        const int ibase = i0 + s * 16 + lg * 4;
        float es = 0.f;
#pragma unroll
        for (int r = 0; r < 4; ++r)
          es += (ibase + r >= jg) ? __expf(s4[r]) : 0.f;   // causal predicate
        es += __shfl_xor(es, 16);
        es += __shfl_xor(es, 32);
        z += es;
      }
      __syncthreads();
      cur ^= 1;
    }
#undef STAGE_Q
    if (lg == 0) zout[jg] = z;                     // wave-local, no barrier
  }
  grid.sync();

  // ===== Phase 3: output partials (R23 body, NPART=2) =====
  {
    __bf16 (*KT)[64][64] = reinterpret_cast<__bf16(*)[64][64]>(smem);
    __bf16 (*VT)[64][64] = reinterpret_cast<__bf16(*)[64][64]>(smem + 16384);
    __bf16 (*P)[16][72]  = reinterpret_cast<__bf16(*)[16][72]>(smem + 32768);

    const int b  = blk & 7;
    const int ib = (blk >> 3) & 15;                // 128-row q-tile
    const int h  = blk >> 7;                       // 0..1
    const int s = t >> 6;                          // wave = strip 0..7
    const int i0 = ib * 128;

    const int n = 2 * ib + 2;                      // j-tiles (even, >= 2)
    const int jbStart = (n * h) / NPART;
    const int jbEnd   = (n * (h + 1)) / NPART;

    float* op = opart + (size_t)h * B_N * S_N * D_N + (size_t)b * S_N * D_N;
    const int ibase = i0 + s * 16 + lg * 4;

    f32x4 o[4];
#pragma unroll
    for (int dt = 0; dt < 4; ++dt) o[dt] = {0.f, 0.f, 0.f, 0.f};

    const __bf16* Qp  = Qb + (size_t)b * S_N * 64;
    const __bf16* Kp  = Kb + (size_t)b * S_N * 64;
    const __bf16* Vtb = Vt + (size_t)b * D_N * S_N;
    const float*  zp  = zpart + (size_t)b * S_N;

    const int r0 = t >> 3, c0 = t & 7;
    const int gq = c0 ^ (r0 & 7);

#define STAGE_KV(BUF, TJ0) do { \
      gload16(&KT[BUF][r0][c0 * 8], Kp + (size_t)((TJ0) + r0) * 64 + gq * 8); \
      gload16(&VT[BUF][r0][c0 * 8], Vtb + (size_t)r0 * S_N + (TJ0) + gq * 8); \
    } while (0)

    const int ri = i0 + s * 16 + lr;
    const bf16x8 aq0 = ldfrag(Qp + (size_t)ri * 64 + lg * 8);
    const bf16x8 aq1 = ldfrag(Qp + (size_t)ri * 64 + 32 + lg * 8);

    STAGE_KV(0, jbStart * 64);
    __syncthreads();

    int cur = 0;
    for (int jb = jbStart; jb < jbEnd; ++jb) {
      const int j0 = jb * 64;
      if (jb + 1 < jbEnd) STAGE_KV(cur ^ 1, j0 + 64);
#pragma unroll
      for (int jt = 0; jt < 4; ++jt) {
        const int krow = jt * 16 + lr;
        const bf16x8 bk0 = ldfrag(&KT[cur][krow][(lg ^ (krow & 7)) * 8]);
        const bf16x8 bk1 = ldfrag(&KT[cur][krow][((4 + lg) ^ (krow & 7)) * 8]);
        f32x4 s4 = {0.f, 0.f, 0.f, 0.f};
        s4 = __builtin_amdgcn_mfma_f32_16x16x32_bf16(aq0, bk0, s4, 0, 0, 0);
        s4 = __builtin_amdgcn_mfma_f32_16x16x32_bf16(aq1, bk1, s4, 0, 0, 0);
        const int jg = j0 + jt * 16 + lr;
        const float rz = 1.0f / (zp[jg] + zp[(size_t)B_N * S_N + jg]);
#pragma unroll
        for (int r = 0; r < 4; ++r) {
          const float pv = (jg <= ibase + r) ? __expf(s4[r]) * rz : 0.f;
          P[s][lg * 4 + r][jt * 16 + lr] = (__bf16)pv;
        }
      }
      const bf16x8 ap0 = ldfrag(&P[s][lr][lg * 8]);
      const bf16x8 ap1 = ldfrag(&P[s][lr][32 + lg * 8]);
#pragma unroll
      for (int dt = 0; dt < 4; ++dt) {
        const int vrow = dt * 16 + lr;
        const bf16x8 bv0 = ldfrag(&VT[cur][vrow][(lg ^ (vrow & 7)) * 8]);
        const bf16x8 bv1 = ldfrag(&VT[cur][vrow][((4 + lg) ^ (vrow & 7)) * 8]);
        o[dt] = __builtin_amdgcn_mfma_f32_16x16x32_bf16(ap0, bv0, o[dt], 0, 0, 0);
        o[dt] = __builtin_amdgcn_mfma_f32_16x16x32_bf16(ap1, bv1, o[dt], 0, 0, 0);
      }
      __syncthreads();
      cur ^= 1;
    }
#undef STAGE_KV

#pragma unroll
    for (int dt = 0; dt < 4; ++dt)
#pragma unroll
      for (int r = 0; r < 4; ++r)
        op[(size_t)(ibase + r) * D_N + dt * 16 + lr] = o[dt][r];
  }
  grid.sync();

  // ===== Phase 4: combine the 2 halves -> out =====
  {
    const size_t stride = (size_t)B_N * S_N * D_N;
    const int gtid = blk * 512 + t;
    for (size_t idx4 = gtid; idx4 < stride / 4; idx4 += 256 * 512) {
      const float4 a = *reinterpret_cast<const float4*>(opart + idx4 * 4);
      const float4 b = *reinterpret_cast<const float4*>(opart + stride + idx4 * 4);
      float4 r;
      r.x = a.x + b.x; r.y = a.y + b.y; r.z = a.z + b.z; r.w = a.w + b.w;
      *reinterpret_cast<float4*>(out + idx4 * 4) = r;
    }
  }
}

extern "C" void kernel_launch(void* const* d_in, const int* in_sizes, int n_in,
                              void* d_out, int out_size, void* d_ws, size_t ws_size,
                              hipStream_t stream) {
  (void)in_sizes; (void)n_in; (void)ws_size; (void)out_size;
  const float* x  = (const float*)d_in[0];
  const float* Wq = (const float*)d_in[1];
  const float* Wk = (const float*)d_in[2];
  const float* Wv = (const float*)d_in[3];
  float* out = (float*)d_out;

  __bf16* Qb = (__bf16*)d_ws;                         // [B*S][64] pre-scaled
  __bf16* Kb = Qb + (size_t)B_N * S_N * D_N;          // [B*S][64]
  __bf16* Vt = Kb + (size_t)B_N * S_N * D_N;          // [B][64][S] transposed
  float* zpart = (float*)(Vt + (size_t)B_N * S_N * D_N); // [NPART][B][S]
  float* opart = zpart + (size_t)NPART * B_N * S_N;      // [NPART][B][S][64]
  __bf16* Wt = (__bf16*)(opart + (size_t)NPART * B_N * S_N * D_N); // [3][64][384]
  __bf16* xbuf = Wt + (size_t)3 * 64 * C_N;              // [B*S][384] bf16

  void* args[] = {(void*)&x, (void*)&Wq, (void*)&Wk, (void*)&Wv,
                  (void*)&xbuf, (void*)&Wt, (void*)&Qb, (void*)&Kb, (void*)&Vt,
                  (void*)&zpart, (void*)&opart, (void*)&out};
  hipLaunchCooperativeKernel((const void*)fused, dim3(256), dim3(512), args, 0,
                             stream);
}

// Round 27
// 74.010 us; speedup vs baseline: 2.7584x; 2.7584x over previous
//
#include <hip/hip_runtime.h>
#include <hip/hip_bf16.h>
#include <math.h>

#define B_N 8
#define S_N 2048
#define C_N 384
#define D_N 64
#define NPART 4           // triangular split factor
#define NEG_BIG (-1e30f)

typedef __bf16 bf16x8 __attribute__((ext_vector_type(8)));
typedef float f32x4 __attribute__((ext_vector_type(4)));

static __device__ __forceinline__ bf16x8 ldfrag(const __bf16* p) {
  return *reinterpret_cast<const bf16x8*>(p);
}

// async 16B global -> LDS (linear dest, per-lane global src)
static __device__ __forceinline__ void gload16(void* lds, const void* gsrc) {
  __builtin_amdgcn_global_load_lds(
      (const __attribute__((address_space(1))) unsigned int*)gsrc,
      (__attribute__((address_space(3))) unsigned int*)lds, 16, 0, 0);
}

// ---------------------------------------------------------------------------
// Kernel 0: weight prep. Wt[m][d][c] = (bf16) W_m[c][d].
// ---------------------------------------------------------------------------
__global__ __launch_bounds__(256) void w_prep(
    const float* __restrict__ Wq, const float* __restrict__ Wk,
    const float* __restrict__ Wv, __bf16* __restrict__ Wt) {
  const int idx = blockIdx.x * 256 + threadIdx.x;   // [0, 3*64*384)
  const int m = idx / (64 * C_N);
  const int r = idx % (64 * C_N);
  const int d = r / C_N;
  const int c = r % C_N;
  const float* W = (m == 0) ? Wq : (m == 1) ? Wk : Wv;
  Wt[idx] = (__bf16)W[c * 64 + d];
}

// ---------------------------------------------------------------------------
// Kernel 1: QKV projection via MFMA, x and W register-prefetched (R19).
// ---------------------------------------------------------------------------
__global__ __launch_bounds__(384) void qkv_mfma(
    const float* __restrict__ x, const __bf16* __restrict__ Wt,
    __bf16* __restrict__ Q, __bf16* __restrict__ K, __bf16* __restrict__ Vt) {
  const int t = threadIdx.x;
  const int w = t >> 6, lane = t & 63, lr = lane & 15, lg = lane >> 4;
  const int mat = w >> 1, rh = w & 1;
  const int row0 = blockIdx.x * 32;                 // flat row in [0, B*S)
  const int ri = row0 + rh * 16 + lr;

  __shared__ __bf16 vtile[32][66];                  // V block, padded

  const float scl = (mat == 0) ? 0.125f : 1.0f;
  const float* xr = x + (size_t)ri * C_N;
  const __bf16* Wm = Wt + (size_t)mat * 64 * C_N;

  f32x4 acc[4];
#pragma unroll
  for (int nt = 0; nt < 4; ++nt) acc[nt] = {0.f, 0.f, 0.f, 0.f};

  float4 xa = *reinterpret_cast<const float4*>(xr + lg * 8);
  float4 xb = *reinterpret_cast<const float4*>(xr + lg * 8 + 4);
  bf16x8 bw[4];
#pragma unroll
  for (int nt = 0; nt < 4; ++nt)
    bw[nt] = ldfrag(Wm + (size_t)(nt * 16 + lr) * C_N + lg * 8);

  for (int kk = 0; kk < C_N / 32; ++kk) {
    const int kn = (kk + 1 < C_N / 32) ? kk + 1 : kk;
    const float4 xan = *reinterpret_cast<const float4*>(xr + kn * 32 + lg * 8);
    const float4 xbn = *reinterpret_cast<const float4*>(xr + kn * 32 + lg * 8 + 4);
    bf16x8 bwn[4];
#pragma unroll
    for (int nt = 0; nt < 4; ++nt)
      bwn[nt] = ldfrag(Wm + (size_t)(nt * 16 + lr) * C_N + kn * 32 + lg * 8);

    bf16x8 a;
    a[0] = (__bf16)(xa.x * scl); a[1] = (__bf16)(xa.y * scl);
    a[2] = (__bf16)(xa.z * scl); a[3] = (__bf16)(xa.w * scl);
    a[4] = (__bf16)(xb.x * scl); a[5] = (__bf16)(xb.y * scl);
    a[6] = (__bf16)(xb.z * scl); a[7] = (__bf16)(xb.w * scl);
#pragma unroll
    for (int nt = 0; nt < 4; ++nt)
      acc[nt] = __builtin_amdgcn_mfma_f32_16x16x32_bf16(a, bw[nt], acc[nt], 0, 0, 0);

    xa = xan; xb = xbn;
#pragma unroll
    for (int nt = 0; nt < 4; ++nt) bw[nt] = bwn[nt];
  }

  if (mat < 2) {
    __bf16* outp = (mat == 0) ? Q : K;
#pragma unroll
    for (int nt = 0; nt < 4; ++nt)
#pragma unroll
      for (int r = 0; r < 4; ++r)
        outp[(size_t)(row0 + rh * 16 + lg * 4 + r) * 64 + nt * 16 + lr] =
            (__bf16)acc[nt][r];
  } else {
#pragma unroll
    for (int nt = 0; nt < 4; ++nt)
#pragma unroll
      for (int r = 0; r < 4; ++r)
        vtile[rh * 16 + lg * 4 + r][nt * 16 + lr] = (__bf16)acc[nt][r];
  }
  __syncthreads();

  const int b = row0 >> 11, s0 = row0 & (S_N - 1);
  for (int idx = t; idx < 64 * 32; idx += 384) {
    const int d = idx >> 5, s2 = idx & 31;
    Vt[((size_t)b * D_N + d) * S_N + s0 + s2] = vtile[s2][d];
  }
}

// ---------------------------------------------------------------------------
// Kernel 2: column denominator PARTIALS (m == 0). Grid (b, jb, h), 256 thr =
// 4 waves; wave q owns j-tile q over ALL 4 i-strips -> z stays in registers,
// no cross-wave sharing. ONE 4-wave barrier per i-tile.
// ---------------------------------------------------------------------------
__global__ __launch_bounds__(256) void col_stats(
    const __bf16* __restrict__ Q, const __bf16* __restrict__ K,
    float* __restrict__ zpart) {
  const int wg = blockIdx.x;                       // 1024 blocks
  const int b  = wg & 7;                           // XCD swizzle
  const int jb = (wg >> 3) & 31;                   // 0..31
  const int h  = wg >> 8;                          // 0..3
  const int j0 = jb * 64;

  const int t = threadIdx.x;
  const int q = t >> 6;                            // wave = j-tile 0..3
  const int lane = t & 63, lr = lane & 15, lg = lane >> 4;

  const int n = 32 - jb;
  const int itStart = jb + (n * h) / NPART;
  const int itEnd   = jb + (n * (h + 1)) / NPART;
  float* zout = zpart + (size_t)h * B_N * S_N + (size_t)b * S_N;

  if (itStart >= itEnd) {                          // empty part: zero partials
    if (lg == 0) zout[j0 + q * 16 + lr] = 0.f;
    return;
  }

  __shared__ __align__(16) __bf16 QT[2][64][64];   // source-swizzled rows

  const __bf16* Qb = Q + (size_t)b * S_N * 64;
  const __bf16* Kb = K + (size_t)b * S_N * 64;

  // K fragments for j-tile q (fixed for the whole block)
  const int krow = j0 + q * 16 + lr;
  const bf16x8 bk0 = ldfrag(Kb + (size_t)krow * 64 + lg * 8);
  const bf16x8 bk1 = ldfrag(Kb + (size_t)krow * 64 + 32 + lg * 8);

  // staging: 512 chunks / 256 threads = 2 each (rows r0 and r0+32)
  const int r0 = t >> 3, c0 = t & 7;
  const int gq = c0 ^ (r0 & 7);                    // same for r0+32

#define STAGE_Q(BUF, TILE) do { \
    gload16(&QT[BUF][r0][c0 * 8], Qb + (size_t)((TILE) * 64 + r0) * 64 + gq * 8); \
    gload16(&QT[BUF][r0 + 32][c0 * 8], \
            Qb + (size_t)((TILE) * 64 + r0 + 32) * 64 + gq * 8); \
  } while (0)

  STAGE_Q(0, itStart);
  __syncthreads();

  float z = 0.f;
  int cur = 0;
  for (int it = itStart; it < itEnd; ++it) {
    const int i0 = it * 64;
    if (it + 1 < itEnd) STAGE_Q(cur ^ 1, it + 1);  // full iteration to land

#pragma unroll
    for (int s = 0; s < 4; ++s) {
      const int arow = s * 16 + lr;
      const bf16x8 aq0 = ldfrag(&QT[cur][arow][(lg ^ (arow & 7)) * 8]);
      const bf16x8 aq1 = ldfrag(&QT[cur][arow][((4 + lg) ^ (arow & 7)) * 8]);
      f32x4 s4 = {0.f, 0.f, 0.f, 0.f};
      s4 = __builtin_amdgcn_mfma_f32_16x16x32_bf16(aq0, bk0, s4, 0, 0, 0);
      s4 = __builtin_amdgcn_mfma_f32_16x16x32_bf16(aq1, bk1, s4, 0, 0, 0);
      const int ibase = i0 + s * 16 + lg * 4;      // D-row base
      const int jg = j0 + q * 16 + lr;             // D col
      if (it == jb) {                              // diagonal tile mask
#pragma unroll
        for (int r = 0; r < 4; ++r)
          if (ibase + r < jg) s4[r] = NEG_BIG;     // expf -> 0
      }
      float es = __expf(s4[0]) + __expf(s4[1]) + __expf(s4[2]) + __expf(s4[3]);
      es += __shfl_xor(es, 16);
      es += __shfl_xor(es, 32);
      z += es;
    }

    __syncthreads();   // QT[cur] reads done; next tile's DMA drained
    cur ^= 1;
  }
#undef STAGE_Q

  if (lg == 0) zout[j0 + q * 16 + lr] = z;         // wave-local, no barrier
}

// ---------------------------------------------------------------------------
// Kernel 3: output pass PARTIALS. Grid (b, ib, h), 256 thr = 4 waves; wave s
// owns strip s: full P (private LDS region, same-wave DS ordering) and full
// PV (o[4] accumulators). ONE 4-wave barrier per jb-tile.
// ---------------------------------------------------------------------------
__global__ __launch_bounds__(256) void attn_out(
    const __bf16* __restrict__ Q, const __bf16* __restrict__ K,
    const __bf16* __restrict__ Vt, const float* __restrict__ zpart,
    float* __restrict__ opart) {
  const int wg = blockIdx.x;                       // 1024 blocks
  const int b  = wg & 7;                           // XCD swizzle
  const int ib = (wg >> 3) & 31;                   // 0..31
  const int h  = wg >> 8;                          // 0..3

  const int t = threadIdx.x;
  const int s = t >> 6;                            // wave = strip 0..3
  const int lane = t & 63, lr = lane & 15, lg = lane >> 4;
  const int i0 = ib * 64;

  const int n = ib + 1;
  const int jbStart = (n * h) / NPART;
  const int jbEnd   = (n * (h + 1)) / NPART;

  float* op = opart + (size_t)h * B_N * S_N * D_N + (size_t)b * S_N * D_N;
  const int ibase = i0 + s * 16 + lg * 4;          // D-row base

  f32x4 o[4];
#pragma unroll
  for (int dt = 0; dt < 4; ++dt) o[dt] = {0.f, 0.f, 0.f, 0.f};

  if (jbStart < jbEnd) {
    __shared__ __align__(16) __bf16 KT[2][64][64];
    __shared__ __align__(16) __bf16 VT[2][64][64];
    __shared__ __align__(16) __bf16 P[4][16][72];  // per-wave private strips

    const __bf16* Qb  = Q  + (size_t)b * S_N * 64;
    const __bf16* Kb  = K  + (size_t)b * S_N * 64;
    const __bf16* Vtb = Vt + (size_t)b * D_N * S_N;
    const float*  zp  = zpart + (size_t)b * S_N;

    // staging: 1024 chunks / 256 threads = 4 each (K r0, r0+32; V r0, r0+32)
    const int r0 = t >> 3, c0 = t & 7;
    const int gq = c0 ^ (r0 & 7);

#define STAGE_KV(BUF, TJ0) do { \
      gload16(&KT[BUF][r0][c0 * 8], Kb + (size_t)((TJ0) + r0) * 64 + gq * 8); \
      gload16(&KT[BUF][r0 + 32][c0 * 8], \
              Kb + (size_t)((TJ0) + r0 + 32) * 64 + gq * 8); \
      gload16(&VT[BUF][r0][c0 * 8], Vtb + (size_t)r0 * S_N + (TJ0) + gq * 8); \
      gload16(&VT[BUF][r0 + 32][c0 * 8], \
              Vtb + (size_t)(r0 + 32) * S_N + (TJ0) + gq * 8); \
    } while (0)

    // Q fragments (registers, live whole kernel)
    const int ri = i0 + s * 16 + lr;
    const bf16x8 aq0 = ldfrag(Qb + (size_t)ri * 64 + lg * 8);
    const bf16x8 aq1 = ldfrag(Qb + (size_t)ri * 64 + 32 + lg * 8);

    STAGE_KV(0, jbStart * 64);
    __syncthreads();

    int cur = 0;
    for (int jb = jbStart; jb < jbEnd; ++jb) {
      const int j0 = jb * 64;
      if (jb + 1 < jbEnd) STAGE_KV(cur ^ 1, j0 + 64);  // full iteration to land

      // ---- QK + P for the whole strip (wave-local) ----
#pragma unroll
      for (int jt = 0; jt < 4; ++jt) {
        const int krow = jt * 16 + lr;
        const bf16x8 bk0 = ldfrag(&KT[cur][krow][(lg ^ (krow & 7)) * 8]);
        const bf16x8 bk1 = ldfrag(&KT[cur][krow][((4 + lg) ^ (krow & 7)) * 8]);
        f32x4 s4 = {0.f, 0.f, 0.f, 0.f};
        s4 = __builtin_amdgcn_mfma_f32_16x16x32_bf16(aq0, bk0, s4, 0, 0, 0);
        s4 = __builtin_amdgcn_mfma_f32_16x16x32_bf16(aq1, bk1, s4, 0, 0, 0);
        const int jg = j0 + jt * 16 + lr;          // D col
        const float rz = 1.0f / (zp[jg] + zp[(size_t)B_N * S_N + jg] +
                                 zp[(size_t)2 * B_N * S_N + jg] +
                                 zp[(size_t)3 * B_N * S_N + jg]);
#pragma unroll
        for (int r = 0; r < 4; ++r) {
          const float pv = (jg <= ibase + r) ? __expf(s4[r]) * rz : 0.f;
          P[s][lg * 4 + r][jt * 16 + lr] = (__bf16)pv;
        }
      }

      // ---- PV from own P strip (same-wave DS ordering, no barrier) ----
      const bf16x8 ap0 = ldfrag(&P[s][lr][lg * 8]);
      const bf16x8 ap1 = ldfrag(&P[s][lr][32 + lg * 8]);
#pragma unroll
      for (int dt = 0; dt < 4; ++dt) {
        const int vrow = dt * 16 + lr;
        const bf16x8 bv0 = ldfrag(&VT[cur][vrow][(lg ^ (vrow & 7)) * 8]);
        const bf16x8 bv1 = ldfrag(&VT[cur][vrow][((4 + lg) ^ (vrow & 7)) * 8]);
        o[dt] = __builtin_amdgcn_mfma_f32_16x16x32_bf16(ap0, bv0, o[dt], 0, 0, 0);
        o[dt] = __builtin_amdgcn_mfma_f32_16x16x32_bf16(ap1, bv1, o[dt], 0, 0, 0);
      }

      __syncthreads();   // tile[cur] reads done; next tile's DMA drained
      cur ^= 1;
    }
#undef STAGE_KV
  }

#pragma unroll
  for (int dt = 0; dt < 4; ++dt)
#pragma unroll
    for (int r = 0; r < 4; ++r)
      op[(size_t)(ibase + r) * D_N + dt * 16 + lr] = o[dt][r];
}

// ---------------------------------------------------------------------------
// Kernel 4: combine the NPART attn_out partials. out = sum_h opart[h].
// ---------------------------------------------------------------------------
__global__ __launch_bounds__(256) void combine(
    const float* __restrict__ opart, float* __restrict__ out) {
  const size_t idx = (size_t)blockIdx.x * 256 + threadIdx.x;
  const size_t stride = (size_t)B_N * S_N * D_N;
  out[idx] = opart[idx] + opart[stride + idx] + opart[2 * stride + idx] +
             opart[3 * stride + idx];
}

extern "C" void kernel_launch(void* const* d_in, const int* in_sizes, int n_in,
                              void* d_out, int out_size, void* d_ws, size_t ws_size,
                              hipStream_t stream) {
  (void)in_sizes; (void)n_in; (void)ws_size; (void)out_size;
  const float* x  = (const float*)d_in[0];
  const float* Wq = (const float*)d_in[1];
  const float* Wk = (const float*)d_in[2];
  const float* Wv = (const float*)d_in[3];
  float* out = (float*)d_out;

  __bf16* Qb = (__bf16*)d_ws;                         // [B*S][64] pre-scaled
  __bf16* Kb = Qb + (size_t)B_N * S_N * D_N;          // [B*S][64]
  __bf16* Vt = Kb + (size_t)B_N * S_N * D_N;          // [B][64][S] transposed
  float* zpart = (float*)(Vt + (size_t)B_N * S_N * D_N); // [NPART][B][S]
  float* opart = zpart + (size_t)NPART * B_N * S_N;      // [NPART][B][S][64]
  __bf16* Wt = (__bf16*)(opart + (size_t)NPART * B_N * S_N * D_N); // [3][64][384]

  w_prep<<<dim3(3 * 64 * C_N / 256), dim3(256), 0, stream>>>(Wq, Wk, Wv, Wt);
  qkv_mfma<<<dim3(B_N * S_N / 32), dim3(384), 0, stream>>>(x, Wt, Qb, Kb, Vt);
  col_stats<<<dim3(NPART * 32 * B_N), dim3(256), 0, stream>>>(Qb, Kb, zpart);
  attn_out<<<dim3(NPART * 32 * B_N), dim3(256), 0, stream>>>(Qb, Kb, Vt, zpart, opart);
  combine<<<dim3(B_N * S_N * D_N / 256), dim3(256), 0, stream>>>(opart, out);
}